// Round 1
// baseline (189.715 us; speedup 1.0000x reference)
//
#include <hip/hip_runtime.h>

// Fused causal attention head: B=8, T=2048, C=1024, H=128 (fp32 in/out).
//   q,k,v = x@W{q,k,v};  out = softmax(tril(q k^T * C^-0.5)) @ v
// Pipeline:
//   prep_wt : W (1024x128 fp32) -> Wt bf16 [384][1024] (transposed; Wq pre-scaled
//             by C^-0.5 * log2(e) so softmax runs in exp2 domain)
//   proj    : X@W via 16x16x32 bf16 MFMA -> Qb,Kb bf16 [16384][128], VT bf16 [8][128][2048]
//   attn    : flash attention, 16 q-rows per wave, K/V frags direct from L2.
// Workspace layout (needs ~13 MB):
//   [0,768K)   Wt   [1M,5M) Qb   [5M,9M) Kb   [9M,13M) VT

#define B_ 8
#define T_ 2048
#define C_ 1024
#define H_ 128

typedef __attribute__((ext_vector_type(4))) float  f32x4;
typedef __attribute__((ext_vector_type(8))) __bf16 bf16x8;

#define QSCALE (0.03125f * 1.44269504088896340736f)  // C^-0.5 * log2(e)

static __device__ __forceinline__ short f2bf(float f) {
  union { __bf16 b; short s; } u;
  u.b = (__bf16)f;
  return u.s;
}

static __device__ __forceinline__ void gload_lds16(const void* g, void* l) {
  __builtin_amdgcn_global_load_lds(
      (const __attribute__((address_space(1))) unsigned int*)g,
      (__attribute__((address_space(3))) unsigned int*)l, 16, 0, 0);
}

// ---------------- prep: Wt[n][k] = W_sel[k][n%128] * (n<128 ? QSCALE : 1) ---------
__global__ void prep_wt(const float* __restrict__ Wq, const float* __restrict__ Wk,
                        const float* __restrict__ Wv, short* __restrict__ Wt) {
  int n = blockIdx.x;  // 0..383
  const float* W = (n < 128) ? Wq : (n < 256 ? Wk : Wv);
  int col = n & 127;
  float s = (n < 128) ? QSCALE : 1.0f;
  for (int k = threadIdx.x; k < C_; k += blockDim.x)
    Wt[(size_t)n * C_ + k] = f2bf(W[(size_t)k * H_ + col] * s);
}

// ---------------- proj: 64 rows x 384 cols per block, BK=128 ----------------------
// 8 waves: wr = wave>>2 (row half, 32 rows), wc = wave&3 (96-col group).
// A tile [64][128] fp32 in LDS, 16B-slot XOR-swizzled (slot ^= row&7).
__global__ __launch_bounds__(512) void proj(const float* __restrict__ x,
                                            const short* __restrict__ Wt,
                                            short* __restrict__ Qb,
                                            short* __restrict__ Kb,
                                            short* __restrict__ VT) {
  __shared__ __align__(16) float At[64 * 128];  // 32 KB
  const int tid = threadIdx.x, lane = tid & 63, wv = tid >> 6;
  const int wr = wv >> 2, wc = wv & 3;
  const int cg = lane & 15, rg = lane >> 4;
  const int m0 = blockIdx.x * 64;
  const float* xblk = x + (size_t)m0 * C_;

  f32x4 acc[2][6];
#pragma unroll
  for (int i = 0; i < 2; ++i)
#pragma unroll
    for (int j = 0; j < 6; ++j) {
      f32x4 z = {0.f, 0.f, 0.f, 0.f};
      acc[i][j] = z;
    }

  for (int kk = 0; kk < C_; kk += 128) {
    if (kk) __syncthreads();
    // stage A: 2048 slots of 16B; dest linear, source pre-swizzled
#pragma unroll
    for (int it = 0; it < 4; ++it) {
      int slotbase = it * 512 + wv * 64;       // wave-uniform
      int slot = slotbase + lane;
      int r = slot >> 5, s = slot & 31;        // 32 slots (128 floats) per row
      gload_lds16(xblk + (size_t)r * C_ + kk + ((s ^ (r & 7)) << 2),
                  &At[slotbase * 4]);
    }
    __syncthreads();

#pragma unroll
    for (int ks = 0; ks < 4; ++ks) {           // k-slices of 32 within BK=128
      bf16x8 af[2];
#pragma unroll
      for (int rf = 0; rf < 2; ++rf) {
        int r = wr * 32 + rf * 16 + cg;
        int s0 = ks * 8 + rg * 2;
        f32x4 a0 = *(const f32x4*)&At[r * 128 + (((s0    ) ^ (r & 7)) << 2)];
        f32x4 a1 = *(const f32x4*)&At[r * 128 + (((s0 + 1) ^ (r & 7)) << 2)];
        bf16x8 t;
        t[0] = (__bf16)a0[0]; t[1] = (__bf16)a0[1];
        t[2] = (__bf16)a0[2]; t[3] = (__bf16)a0[3];
        t[4] = (__bf16)a1[0]; t[5] = (__bf16)a1[1];
        t[6] = (__bf16)a1[2]; t[7] = (__bf16)a1[3];
        af[rf] = t;
      }
#pragma unroll
      for (int nf = 0; nf < 6; ++nf) {
        int n = wc * 96 + nf * 16 + cg;
        bf16x8 bfr = *(const bf16x8*)&Wt[(size_t)n * C_ + kk + ks * 32 + rg * 8];
        acc[0][nf] = __builtin_amdgcn_mfma_f32_16x16x32_bf16(af[0], bfr, acc[0][nf], 0, 0, 0);
        acc[1][nf] = __builtin_amdgcn_mfma_f32_16x16x32_bf16(af[1], bfr, acc[1][nf], 0, 0, 0);
      }
    }
  }

  // epilogue: D frag is row=(lane>>4)*4+r, col=lane&15
#pragma unroll
  for (int rf = 0; rf < 2; ++rf) {
#pragma unroll
    for (int nf = 0; nf < 6; ++nf) {
      int n = wc * 96 + nf * 16 + cg;
      int rowb = m0 + wr * 32 + rf * 16 + rg * 4;
      f32x4 v = acc[rf][nf];
      if (n < 128) {
#pragma unroll
        for (int r = 0; r < 4; ++r)
          Qb[(size_t)(rowb + r) * H_ + n] = f2bf(v[r]);
      } else if (n < 256) {
#pragma unroll
        for (int r = 0; r < 4; ++r)
          Kb[(size_t)(rowb + r) * H_ + (n - 128)] = f2bf(v[r]);
      } else {
        int h = n - 256;
#pragma unroll
        for (int r = 0; r < 4; ++r) {
          int m = rowb + r;
          VT[((size_t)((m >> 11) * H_ + h)) * T_ + (m & (T_ - 1))] = f2bf(v[r]);
        }
      }
    }
  }
}

// ---------------- attn: flash attention, 16 q rows per wave -----------------------
// grid (32, 8): blockIdx.x = q-tile of 64, blockIdx.y = batch; 4 waves/block.
__global__ __launch_bounds__(256) void attn(const short* __restrict__ Qb,
                                            const short* __restrict__ Kb,
                                            const short* __restrict__ VT,
                                            float* __restrict__ out) {
  __shared__ __align__(16) short Pl[4][16 * 64];  // per-wave P buffer, swizzled
  const int tid = threadIdx.x, lane = tid & 63, wv = tid >> 6;
  const int cg = lane & 15, rg = lane >> 4;
  const int b = blockIdx.y;
  const int q0 = blockIdx.x * 64 + wv * 16;
  const short* Qp = Qb + (size_t)(b * T_ + q0) * H_;
  const short* Kp = Kb + (size_t)(b * T_) * H_;
  const short* Vp = VT + (size_t)(b * H_) * T_;
  short* Pw = &Pl[wv][0];
  const float NEG_INF = -__builtin_inff();

  // Q frags stay in registers: A[row=lane&15][k = ks*32 + (lane>>4)*8 + j]
  bf16x8 qf[4];
#pragma unroll
  for (int ks = 0; ks < 4; ++ks)
    qf[ks] = *(const bf16x8*)&Qp[(size_t)cg * H_ + ks * 32 + rg * 8];

  f32x4 o[8];
#pragma unroll
  for (int f = 0; f < 8; ++f) { f32x4 z = {0.f, 0.f, 0.f, 0.f}; o[f] = z; }
  float m[4], lsum[4];
#pragma unroll
  for (int r = 0; r < 4; ++r) { m[r] = NEG_INF; lsum[r] = 0.0f; }

  const int ntiles = (q0 >> 6) + 1;  // kv tiles of 64 up to q0+15
  for (int t = 0; t < ntiles; ++t) {
    const int kv0 = t * 64;
    f32x4 S[4];
#pragma unroll
    for (int nf = 0; nf < 4; ++nf) { f32x4 z = {0.f, 0.f, 0.f, 0.f}; S[nf] = z; }

    // S = Q K^T (scaled, log2e folded into Q). B frag contiguous from Kb rows.
#pragma unroll
    for (int nf = 0; nf < 4; ++nf) {
#pragma unroll
      for (int ks = 0; ks < 4; ++ks) {
        bf16x8 kfr = *(const bf16x8*)&Kp[(size_t)(kv0 + nf * 16 + cg) * H_ + ks * 32 + rg * 8];
        S[nf] = __builtin_amdgcn_mfma_f32_16x16x32_bf16(qf[ks], kfr, S[nf], 0, 0, 0);
      }
    }

    // causal mask (only the last tile can straddle the diagonal)
    if (t == ntiles - 1) {
#pragma unroll
      for (int nf = 0; nf < 4; ++nf) {
#pragma unroll
        for (int r = 0; r < 4; ++r) {
          int kv = kv0 + nf * 16 + cg;
          int q = q0 + rg * 4 + r;
          if (kv > q) S[nf][r] = NEG_INF;
        }
      }
    }

    // online softmax (exp2 domain); row-max over 16 lanes of the group
    float sf[4];
#pragma unroll
    for (int r = 0; r < 4; ++r) {
      float pm = fmaxf(fmaxf(S[0][r], S[1][r]), fmaxf(S[2][r], S[3][r]));
      pm = fmaxf(pm, __shfl_xor(pm, 1));
      pm = fmaxf(pm, __shfl_xor(pm, 2));
      pm = fmaxf(pm, __shfl_xor(pm, 4));
      pm = fmaxf(pm, __shfl_xor(pm, 8));
      float mn = fmaxf(m[r], pm);
      sf[r] = exp2f(m[r] - mn);   // m=-inf -> 0; mn always finite (kv=0 <= q)
      m[r] = mn;
      lsum[r] *= sf[r];
    }

    // P = exp2(S - m), write bf16 to per-wave LDS (16B-slot swizzle: slot ^= row&7)
#pragma unroll
    for (int nf = 0; nf < 4; ++nf) {
#pragma unroll
      for (int r = 0; r < 4; ++r) {
        float p = exp2f(S[nf][r] - m[r]);
        lsum[r] += p;   // per-lane partial; reduced at the end
        int row = rg * 4 + r, col = nf * 16 + cg;
        Pw[row * 64 + ((((col >> 3) ^ (row & 7))) << 3) + (col & 7)] = f2bf(p);
      }
    }

    // rescale O accumulator
#pragma unroll
    for (int f = 0; f < 8; ++f) {
#pragma unroll
      for (int r = 0; r < 4; ++r) o[f][r] *= sf[r];
    }

    // O += P V : A frag from P-LDS (contiguous after swizzle), B frag from VT rows
#pragma unroll
    for (int ksl = 0; ksl < 2; ++ksl) {
      int slot = ksl * 4 + rg;
      bf16x8 pa = *(const bf16x8*)&Pw[cg * 64 + ((slot ^ (cg & 7)) << 3)];
#pragma unroll
      for (int hf = 0; hf < 8; ++hf) {
        bf16x8 vb = *(const bf16x8*)&Vp[(size_t)(hf * 16 + cg) * T_ + kv0 + ksl * 32 + rg * 8];
        o[hf] = __builtin_amdgcn_mfma_f32_16x16x32_bf16(pa, vb, o[hf], 0, 0, 0);
      }
    }
  }

  // final: reduce l across the 16-lane group, normalize, store fp32 coalesced
  float linv[4];
#pragma unroll
  for (int r = 0; r < 4; ++r) {
    float l = lsum[r];
    l += __shfl_xor(l, 1);
    l += __shfl_xor(l, 2);
    l += __shfl_xor(l, 4);
    l += __shfl_xor(l, 8);
    linv[r] = 1.0f / l;
  }
#pragma unroll
  for (int hf = 0; hf < 8; ++hf) {
#pragma unroll
    for (int r = 0; r < 4; ++r)
      out[(size_t)(b * T_ + q0 + rg * 4 + r) * H_ + hf * 16 + cg] = o[hf][r] * linv[r];
  }
}

extern "C" void kernel_launch(void* const* d_in, const int* in_sizes, int n_in,
                              void* d_out, int out_size, void* d_ws, size_t ws_size,
                              hipStream_t stream) {
  const float* x  = (const float*)d_in[0];
  const float* Wq = (const float*)d_in[1];
  const float* Wk = (const float*)d_in[2];
  const float* Wv = (const float*)d_in[3];
  float* out = (float*)d_out;
  char* ws = (char*)d_ws;

  short* Wt = (short*)(ws);                          // 768 KB
  short* Qb = (short*)(ws + ((size_t)1 << 20));      // 4 MB
  short* Kb = (short*)(ws + ((size_t)5 << 20));      // 4 MB
  short* VT = (short*)(ws + ((size_t)9 << 20));      // 4 MB  (total 13 MB)

  prep_wt<<<dim3(384), dim3(256), 0, stream>>>(Wq, Wk, Wv, Wt);
  proj<<<dim3(256), dim3(512), 0, stream>>>(x, Wt, Qb, Kb, VT);
  attn<<<dim3(32, 8), dim3(256), 0, stream>>>(Qb, Kb, VT, out);
}

// Round 2
// 172.584 us; speedup vs baseline: 1.0993x; 1.0993x over previous
//
#include <hip/hip_runtime.h>

// Fused causal attention head: B=8, T=2048, C=1024, H=128 (fp32 in/out).
//   q,k,v = x@W{q,k,v};  out = softmax(tril(q k^T * C^-0.5)) @ v
// Pipeline:
//   prep_wt : W (1024x128 fp32) -> Wt bf16 [384][1024] (transposed; Wq pre-scaled
//             by C^-0.5 * log2(e) so softmax runs in exp2 domain)
//   proj    : X@W via 16x16x32 bf16 MFMA, no LDS (A direct from x + cvt, B from
//             L2-resident Wt) -> Qb,Kb bf16 [16384][128], VT bf16 [8][128][2048]
//   attn    : flash attention; 4 waves/block share 16 q-rows, split the kv range
//             4 ways, flash-combine partials in LDS. 1024 blocks -> 4 waves/SIMD.
// Workspace layout (~13 MB): [0,768K) Wt  [1M,5M) Qb  [5M,9M) Kb  [9M,13M) VT

#define B_ 8
#define T_ 2048
#define C_ 1024
#define H_ 128

typedef __attribute__((ext_vector_type(4))) float  f32x4;
typedef __attribute__((ext_vector_type(8))) __bf16 bf16x8;

#define QSCALE (0.03125f * 1.44269504088896340736f)  // C^-0.5 * log2(e)

static __device__ __forceinline__ short f2bf(float f) {
  union { __bf16 b; short s; } u;
  u.b = (__bf16)f;
  return u.s;
}

// ---------------- prep: Wt[n][k] = W_sel[k][n%128] * (n<128 ? QSCALE : 1) ---------
// grid 48 = 3 matrices x 16 k-chunks of 64. LDS transpose: coalesced both sides.
__global__ void prep_wt(const float* __restrict__ Wq, const float* __restrict__ Wk,
                        const float* __restrict__ Wv, short* __restrict__ Wt) {
  __shared__ float L[64 * 129];
  const int mtx = blockIdx.x >> 4, kc = blockIdx.x & 15;
  const int k0 = kc * 64;
  const float* W = (mtx == 0) ? Wq : (mtx == 1 ? Wk : Wv);
  const float s = (mtx == 0) ? QSCALE : 1.0f;
  for (int i = threadIdx.x; i < 64 * 128; i += 256) {
    int kk = i >> 7, c = i & 127;
    L[kk * 129 + c] = W[(size_t)(k0 + kk) * H_ + c] * s;
  }
  __syncthreads();
  for (int i = threadIdx.x; i < 128 * 64; i += 256) {
    int n = i >> 6, kk = i & 63;
    Wt[(size_t)(mtx * 128 + n) * C_ + k0 + kk] = f2bf(L[kk * 129 + n]);
  }
}

// ---------------- proj: 32 rows x 384 cols per block, no LDS ----------------------
// 4 waves; wave wv covers cols [wv*96, wv*96+96), rows m0..m0+31 (2 row-frags).
__global__ __launch_bounds__(256) void proj(const float* __restrict__ x,
                                            const short* __restrict__ Wt,
                                            short* __restrict__ Qb,
                                            short* __restrict__ Kb,
                                            short* __restrict__ VT) {
  const int tid = threadIdx.x, lane = tid & 63, wv = tid >> 6;
  const int cg = lane & 15, rg = lane >> 4;
  const int m0 = blockIdx.x * 32;
  const float* xb = x + (size_t)m0 * C_;

  f32x4 acc[2][6];
#pragma unroll
  for (int i = 0; i < 2; ++i)
#pragma unroll
    for (int j = 0; j < 6; ++j) {
      f32x4 z = {0.f, 0.f, 0.f, 0.f};
      acc[i][j] = z;
    }

#pragma unroll 2
  for (int kk = 0; kk < C_; kk += 32) {
    bf16x8 af[2];
#pragma unroll
    for (int rf = 0; rf < 2; ++rf) {
      const float* p = &xb[(size_t)(rf * 16 + cg) * C_ + kk + rg * 8];
      f32x4 a0 = *(const f32x4*)p;
      f32x4 a1 = *(const f32x4*)(p + 4);
      bf16x8 t;
      t[0] = (__bf16)a0[0]; t[1] = (__bf16)a0[1];
      t[2] = (__bf16)a0[2]; t[3] = (__bf16)a0[3];
      t[4] = (__bf16)a1[0]; t[5] = (__bf16)a1[1];
      t[6] = (__bf16)a1[2]; t[7] = (__bf16)a1[3];
      af[rf] = t;
    }
#pragma unroll
    for (int nf = 0; nf < 6; ++nf) {
      int n = wv * 96 + nf * 16 + cg;
      bf16x8 bfr = *(const bf16x8*)&Wt[(size_t)n * C_ + kk + rg * 8];
      acc[0][nf] = __builtin_amdgcn_mfma_f32_16x16x32_bf16(af[0], bfr, acc[0][nf], 0, 0, 0);
      acc[1][nf] = __builtin_amdgcn_mfma_f32_16x16x32_bf16(af[1], bfr, acc[1][nf], 0, 0, 0);
    }
  }

  // epilogue: D frag row=(lane>>4)*4+r, col=lane&15
#pragma unroll
  for (int rf = 0; rf < 2; ++rf) {
#pragma unroll
    for (int nf = 0; nf < 6; ++nf) {
      int n = wv * 96 + nf * 16 + cg;
      int rowb = m0 + rf * 16 + rg * 4;
      f32x4 v = acc[rf][nf];
      if (n < 128) {
#pragma unroll
        for (int r = 0; r < 4; ++r)
          Qb[(size_t)(rowb + r) * H_ + n] = f2bf(v[r]);
      } else if (n < 256) {
#pragma unroll
        for (int r = 0; r < 4; ++r)
          Kb[(size_t)(rowb + r) * H_ + (n - 128)] = f2bf(v[r]);
      } else {
        int h = n - 256;
#pragma unroll
        for (int r = 0; r < 4; ++r) {
          int m = rowb + r;
          VT[((size_t)((m >> 11) * H_ + h)) * T_ + (m & (T_ - 1))] = f2bf(v[r]);
        }
      }
    }
  }
}

// ---------------- attn: 16 q-rows per block, kv range split across 4 waves --------
// grid 1024: bid&7 = batch (XCD-local K/V), 127-(bid>>3) = q-group (largest first).
__global__ __launch_bounds__(256, 4) void attn(const short* __restrict__ Qb,
                                               const short* __restrict__ Kb,
                                               const short* __restrict__ VT,
                                               float* __restrict__ out) {
  __shared__ __align__(16) float OC[4][16 * 128];   // 32 KB; P aliased on top
  __shared__ float Mml[4][16], Lml[4][16];
  const int tid = threadIdx.x, lane = tid & 63, wv = tid >> 6;
  const int cg = lane & 15, rg = lane >> 4;
  const int bid = blockIdx.x;
  const int b = bid & 7;
  const int qg = 127 - (bid >> 3);
  const int q0 = qg << 4;
  const int NT = (qg + 4) >> 2;          // ceil((q0+16)/64) kv-tiles of 64
  const int SPW = (NT + 3) >> 2;         // tiles per wave
  const int t0 = wv * SPW;
  const int t1 = (t0 + SPW < NT) ? (t0 + SPW) : NT;

  const short* Qp = Qb + (size_t)(b * T_ + q0) * H_;
  const short* Kp = Kb + (size_t)(b * T_) * H_;
  const short* Vp = VT + (size_t)(b * H_) * T_;
  short* Pw = (short*)&OC[wv][0];        // 2 KB per-wave P buffer (alias, swizzled)
  const float NEG_INF = -__builtin_inff();

  // Q frags: A[row=lane&15][k = ks*32 + (lane>>4)*8 + j]
  bf16x8 qf[4];
#pragma unroll
  for (int ks = 0; ks < 4; ++ks)
    qf[ks] = *(const bf16x8*)&Qp[(size_t)cg * H_ + ks * 32 + rg * 8];

  f32x4 o[8];
#pragma unroll
  for (int f = 0; f < 8; ++f) { f32x4 z = {0.f, 0.f, 0.f, 0.f}; o[f] = z; }
  float m[4], lsum[4];
#pragma unroll
  for (int r = 0; r < 4; ++r) { m[r] = NEG_INF; lsum[r] = 0.0f; }

  for (int t = t0; t < t1; ++t) {
    const int kv0 = t * 64;
    f32x4 S[4];
#pragma unroll
    for (int nf = 0; nf < 4; ++nf) { f32x4 z = {0.f, 0.f, 0.f, 0.f}; S[nf] = z; }

    // S = Q K^T (scale + log2e folded into Q)
#pragma unroll
    for (int nf = 0; nf < 4; ++nf) {
#pragma unroll
      for (int ks = 0; ks < 4; ++ks) {
        bf16x8 kfr = *(const bf16x8*)&Kp[(size_t)(kv0 + nf * 16 + cg) * H_ + ks * 32 + rg * 8];
        S[nf] = __builtin_amdgcn_mfma_f32_16x16x32_bf16(qf[ks], kfr, S[nf], 0, 0, 0);
      }
    }

    // causal mask: only the globally-last tile straddles the diagonal
    if (t == NT - 1) {
#pragma unroll
      for (int nf = 0; nf < 4; ++nf) {
#pragma unroll
        for (int r = 0; r < 4; ++r) {
          int kv = kv0 + nf * 16 + cg;
          int q = q0 + rg * 4 + r;
          if (kv > q) S[nf][r] = NEG_INF;
        }
      }
    }

    // online softmax (exp2 domain); row-max over the 16-lane group
    float sf[4];
#pragma unroll
    for (int r = 0; r < 4; ++r) {
      float pm = fmaxf(fmaxf(S[0][r], S[1][r]), fmaxf(S[2][r], S[3][r]));
      pm = fmaxf(pm, __shfl_xor(pm, 1));
      pm = fmaxf(pm, __shfl_xor(pm, 2));
      pm = fmaxf(pm, __shfl_xor(pm, 4));
      pm = fmaxf(pm, __shfl_xor(pm, 8));
      float mn = fmaxf(m[r], pm);
      sf[r] = exp2f(m[r] - mn);
      m[r] = mn;
      lsum[r] *= sf[r];
    }

    // P = exp2(S - m) -> bf16 in per-wave LDS (16B-slot swizzle: slot ^= row&7)
#pragma unroll
    for (int nf = 0; nf < 4; ++nf) {
#pragma unroll
      for (int r = 0; r < 4; ++r) {
        float p = exp2f(S[nf][r] - m[r]);
        lsum[r] += p;
        int row = rg * 4 + r, col = nf * 16 + cg;
        Pw[row * 64 + ((((col >> 3) ^ (row & 7))) << 3) + (col & 7)] = f2bf(p);
      }
    }

    // rescale O
#pragma unroll
    for (int f = 0; f < 8; ++f) {
#pragma unroll
      for (int r = 0; r < 4; ++r) o[f][r] *= sf[r];
    }

    // O += P V
#pragma unroll
    for (int ksl = 0; ksl < 2; ++ksl) {
      int slot = ksl * 4 + rg;
      bf16x8 pa = *(const bf16x8*)&Pw[cg * 64 + ((slot ^ (cg & 7)) << 3)];
#pragma unroll
      for (int hf = 0; hf < 8; ++hf) {
        bf16x8 vb = *(const bf16x8*)&Vp[(size_t)(hf * 16 + cg) * T_ + kv0 + ksl * 32 + rg * 8];
        o[hf] = __builtin_amdgcn_mfma_f32_16x16x32_bf16(pa, vb, o[hf], 0, 0, 0);
      }
    }
  }

  // per-wave row-sum of l across the 16-lane group
#pragma unroll
  for (int r = 0; r < 4; ++r) {
    float l = lsum[r];
    l += __shfl_xor(l, 1);
    l += __shfl_xor(l, 2);
    l += __shfl_xor(l, 4);
    l += __shfl_xor(l, 8);
    lsum[r] = l;
  }
  if (cg == 0) {
#pragma unroll
    for (int r = 0; r < 4; ++r) {
      Mml[wv][rg * 4 + r] = m[r];
      Lml[wv][rg * 4 + r] = lsum[r];
    }
  }
  // park partial O in LDS (overwrites this wave's P region — loop is done)
#pragma unroll
  for (int hf = 0; hf < 8; ++hf)
#pragma unroll
    for (int r = 0; r < 4; ++r)
      OC[wv][(rg * 4 + r) * 128 + hf * 16 + cg] = o[hf][r];
  __syncthreads();

  // flash-combine the 4 partials, normalize, store fp32 coalesced
  for (int i = tid; i < 16 * 128; i += 256) {
    int row = i >> 7, col = i & 127;
    float m0v = Mml[0][row], m1v = Mml[1][row], m2v = Mml[2][row], m3v = Mml[3][row];
    float ms = fmaxf(fmaxf(m0v, m1v), fmaxf(m2v, m3v));
    float accv = 0.f, lacc = 0.f;
#pragma unroll
    for (int w = 0; w < 4; ++w) {
      float sc = exp2f(Mml[w][row] - ms);
      lacc += sc * Lml[w][row];
      accv += sc * OC[w][row * 128 + col];
    }
    out[(size_t)(b * T_ + q0 + row) * H_ + col] = accv / lacc;
  }
}

extern "C" void kernel_launch(void* const* d_in, const int* in_sizes, int n_in,
                              void* d_out, int out_size, void* d_ws, size_t ws_size,
                              hipStream_t stream) {
  const float* x  = (const float*)d_in[0];
  const float* Wq = (const float*)d_in[1];
  const float* Wk = (const float*)d_in[2];
  const float* Wv = (const float*)d_in[3];
  float* out = (float*)d_out;
  char* ws = (char*)d_ws;

  short* Wt = (short*)(ws);                          // 768 KB
  short* Qb = (short*)(ws + ((size_t)1 << 20));      // 4 MB
  short* Kb = (short*)(ws + ((size_t)5 << 20));      // 4 MB
  short* VT = (short*)(ws + ((size_t)9 << 20));      // 4 MB  (total 13 MB)

  prep_wt<<<dim3(48), dim3(256), 0, stream>>>(Wq, Wk, Wv, Wt);
  proj<<<dim3(512), dim3(256), 0, stream>>>(x, Wt, Qb, Kb, VT);
  attn<<<dim3(1024), dim3(256), 0, stream>>>(Qb, Kb, VT, out);
}